// Round 11
// baseline (407.384 us; speedup 1.0000x reference)
//
#include <hip/hip_runtime.h>
#include <stdint.h>

#define T_SEQ   2048
#define DMODEL  1024
#define NHEADS  16
#define HDIM    64
#define BATCH   4
#define MROWS   (BATCH * T_SEQ)   // 8192
// Q pre-scale: 1/sqrt(64) * log2(e)  (softmax runs in exp2 domain)
#define QSCALE  0.18033688011112042f

typedef __attribute__((ext_vector_type(4))) short bf16x4;
typedef __attribute__((ext_vector_type(8))) short bf16x8;
typedef __attribute__((ext_vector_type(4))) float f32x4;

__device__ __forceinline__ float b2f(unsigned short u) {
    union { unsigned int i; float f; } x;
    x.i = ((unsigned int)u) << 16;
    return x.f;
}

__device__ __forceinline__ unsigned short f2b(float f) {
    union { float f; unsigned int i; } x;
    x.f = f;
    unsigned int r = x.i + 0x7FFFu + ((x.i >> 16) & 1u);  // RNE
    return (unsigned short)(r >> 16);
}

// async global->LDS, 16 B per lane; dest = lds base (wave-uniform) + lane*16
__device__ __forceinline__ void gl_lds16(const unsigned short* g, unsigned short* l) {
    __builtin_amdgcn_global_load_lds(
        (const __attribute__((address_space(1))) void*)g,
        (__attribute__((address_space(3))) void*)l,
        16, 0, 0);
}

// ---------------------------------------------------------------------------
// fp32 -> bf16 elementwise convert
// ---------------------------------------------------------------------------
__global__ __launch_bounds__(256) void cvt_bf16(
    const float* __restrict__ in, unsigned short* __restrict__ out, int n)
{
    const int i = (blockIdx.x * 256 + threadIdx.x) * 4;
    if (i + 3 < n) {
        const float4 v = *(const float4*)(in + i);
        ushort4 o;
        o.x = f2b(v.x); o.y = f2b(v.y); o.z = f2b(v.z); o.w = f2b(v.w);
        *(ushort4*)(out + i) = o;
    }
}

// ---------------------------------------------------------------------------
// fp32 [K][N] -> bf16 [N][K] transpose+convert, 32x32 LDS tile
// ---------------------------------------------------------------------------
__global__ __launch_bounds__(256) void cvt_tr(
    const float* __restrict__ W, unsigned short* __restrict__ WT, int K, int N)
{
    __shared__ unsigned short s[32][33];
    const int n0 = blockIdx.x * 32, k0 = blockIdx.y * 32;
    const int tx = threadIdx.x & 31, ty = threadIdx.x >> 5;   // ty 0..7
    #pragma unroll
    for (int i = 0; i < 4; i++)
        s[ty + 8 * i][tx] = f2b(W[(size_t)(k0 + ty + 8 * i) * N + n0 + tx]);
    __syncthreads();
    #pragma unroll
    for (int i = 0; i < 4; i++)
        WT[(size_t)(n0 + ty + 8 * i) * K + k0 + tx] = s[tx][ty + 8 * i];
}

// ---------------------------------------------------------------------------
// bf16 MFMA GEMM: C[M][N] = A[M][Kd] * BT[N][Kd]^T + bias[N]
// 128x128 tile, BK=32, 256 thr = 4 waves (2x2), each wave 64x64 = 4x4 MFMAs.
// Staging via global_load_lds (16B/lane): LDS dest slot kq at row srow holds
// global chunk (kq - (srow>>1))&3 (swizzle moved to the SOURCE side so dest
// is lane-contiguous as the instruction requires). Frag reads unchanged:
// frd = row*32 + ((quad+(row>>1))&3)*8 -> yields chunk quad at row.
// ---------------------------------------------------------------------------
__global__ __launch_bounds__(256) void gemm_mfma(
    const unsigned short* __restrict__ A,
    const unsigned short* __restrict__ BT,
    const float* __restrict__ bias,
    int N, int Kd, int mode,
    unsigned short* __restrict__ Oq,
    unsigned short* __restrict__ Ok,
    unsigned short* __restrict__ Ov,
    float* __restrict__ Of)
{
    __shared__ __align__(16) unsigned short aS[128 * 32];
    __shared__ __align__(16) unsigned short bS[128 * 32];

    const int tid  = threadIdx.x;
    const int lane = tid & 63;
    const int wave = tid >> 6;
    const int row  = lane & 15;
    const int quad = lane >> 4;
    const int wm   = wave >> 1;
    const int wn   = wave & 1;
    const int m0   = blockIdx.y * 128;
    const int n0   = blockIdx.x * 128;

    const int srow = lane >> 2;                 // 0..15
    const int kq   = lane & 3;
    const int cs   = (kq - (srow >> 1)) & 3;    // source chunk for dest slot kq
    const int frd  = row * 32 + (((quad + (row >> 1)) & 3) * 8);

    f32x4 acc[4][4];
    const f32x4 z = {0.f, 0.f, 0.f, 0.f};
    #pragma unroll
    for (int i = 0; i < 4; i++)
        #pragma unroll
        for (int j = 0; j < 4; j++) acc[i][j] = z;

    for (int k0 = 0; k0 < Kd; k0 += 32) {
        __syncthreads();   // all waves done reading previous tile
        gl_lds16(A  + (size_t)(m0 + wave * 16       + srow) * Kd + k0 + cs * 8, &aS[wave * 512]);
        gl_lds16(A  + (size_t)(m0 + (wave + 4) * 16 + srow) * Kd + k0 + cs * 8, &aS[wave * 512 + 2048]);
        gl_lds16(BT + (size_t)(n0 + wave * 16       + srow) * Kd + k0 + cs * 8, &bS[wave * 512]);
        gl_lds16(BT + (size_t)(n0 + (wave + 4) * 16 + srow) * Kd + k0 + cs * 8, &bS[wave * 512 + 2048]);
        __syncthreads();   // drains vmcnt -> LDS valid

        bf16x8 af[4], bf[4];
        #pragma unroll
        for (int t = 0; t < 4; t++) {
            af[t] = *(const bf16x8*)(aS + (wm * 4 + t) * 512 + frd);
            bf[t] = *(const bf16x8*)(bS + (wn * 4 + t) * 512 + frd);
        }
        #pragma unroll
        for (int i = 0; i < 4; i++)
            #pragma unroll
            for (int j = 0; j < 4; j++)
                acc[i][j] = __builtin_amdgcn_mfma_f32_16x16x32_bf16(af[i], bf[j], acc[i][j], 0, 0, 0);
    }

    if (mode == 0) {
        #pragma unroll
        for (int j = 0; j < 4; j++) {
            const int n  = n0 + wn * 64 + j * 16 + row;
            const float bi = bias[n];
            const int which = n >> 10;
            const int rem   = n & 1023;
            const int h     = rem >> 6;
            const int d     = rem & 63;
            #pragma unroll
            for (int i = 0; i < 4; i++) {
                const int mbase = m0 + wm * 64 + i * 16 + quad * 4;
                #pragma unroll
                for (int r = 0; r < 4; r++) {
                    const int m = mbase + r;
                    const int b = m >> 11;
                    const int t = m & 2047;
                    const int bh = b * NHEADS + h;
                    const float v = acc[i][j][r] + bi;
                    if (which == 0) {
                        Oq[((size_t)bh * T_SEQ + t) * HDIM + d] = f2b(v * QSCALE);
                    } else if (which == 1) {
                        Ok[((size_t)bh * T_SEQ + t) * HDIM + d] = f2b(v);
                    } else {
                        Ov[((size_t)bh * HDIM + d) * T_SEQ + t] = f2b(v);
                    }
                }
            }
        }
    } else {
        #pragma unroll
        for (int j = 0; j < 4; j++) {
            const int n  = n0 + wn * 64 + j * 16 + row;
            const float bi = bias[n];
            #pragma unroll
            for (int i = 0; i < 4; i++) {
                const int mbase = m0 + wm * 64 + i * 16 + quad * 4;
                #pragma unroll
                for (int r = 0; r < 4; r++)
                    Of[(size_t)(mbase + r) * N + n] = acc[i][j][r] + bi;
            }
        }
    }
}

// ---------------------------------------------------------------------------
// MFMA flash attention, LDS-staged K/V via global_load_lds, exp2-domain
// softmax. WG owns q-blocks [64P,+64) (L) and [64(31-P),+64) (H); wave w owns
// 16 q of each. K/V tiles staged with source-side swizzle: LDS row r slot s
// holds global chunk (s-r)&7 -> frag reads rotate across banks (2-way, free).
// Scores arrive in log2 units (QSCALE includes log2e) -> exp2f, no mul.
// Online softmax per wave = flash numerics; ps summed pre-rounding.
// ---------------------------------------------------------------------------
__global__ __launch_bounds__(256) void attn_mfma(
    const unsigned short* __restrict__ Q,   // [bh][t][64] bf16 (scaled)
    const unsigned short* __restrict__ K,   // [bh][t][64] bf16
    const unsigned short* __restrict__ VT,  // [bh][64][T] bf16
    unsigned short* __restrict__ Out)       // [B*T][DMODEL] bf16
{
    __shared__ __align__(16) unsigned short kS[64 * 64];
    __shared__ __align__(16) unsigned short vS[64 * 64];

    const int tid  = threadIdx.x;
    const int lane = tid & 63;
    const int wave = tid >> 6;
    const int row  = lane & 15;
    const int quad = lane >> 4;

    const int bh = blockIdx.x;
    const int b  = bh >> 4;
    const int h  = bh & 15;
    const int P  = blockIdx.y;                 // 0..15
    const int q0L = 64 * P + 16 * wave;
    const int q0H = 64 * (31 - P) + 16 * wave;
    const int kend = 64 * (31 - P) + 64;       // WG-uniform loop bound

    const size_t qkbase = (size_t)bh * T_SEQ * HDIM;
    const size_t vtbase = (size_t)bh * HDIM * T_SEQ;

    // staging: thread covers LDS bytes tid*16 (rows r0=tid>>3) and 4096+tid*16
    // (rows r0+32). Source chunk for dest slot: (slot - row)&7 (32 = 0 mod 8).
    const int r0   = tid >> 3;           // 0..31
    const int slot = tid & 7;
    const int cs   = (slot - r0) & 7;

    const unsigned short* qpL = Q + qkbase + (size_t)(q0L + row) * HDIM + quad * 8;
    const bf16x8 qL0 = *(const bf16x8*)qpL;
    const bf16x8 qL1 = *(const bf16x8*)(qpL + 32);
    const unsigned short* qpH = Q + qkbase + (size_t)(q0H + row) * HDIM + quad * 8;
    const bf16x8 qH0 = *(const bf16x8*)qpH;
    const bf16x8 qH1 = *(const bf16x8*)(qpH + 32);

    const f32x4 z = {0.f, 0.f, 0.f, 0.f};
    f32x4 oL[4] = {z, z, z, z};
    f32x4 oH[4] = {z, z, z, z};
    float mL = -1e30f, lL = 0.f, mH = -1e30f, lH = 0.f;

    for (int kb = 0; kb < kend; kb += 64) {
        __syncthreads();   // previous tile fully consumed
        gl_lds16(K  + qkbase + (size_t)(kb + r0)      * HDIM + cs * 8, &kS[wave * 512]);
        gl_lds16(K  + qkbase + (size_t)(kb + r0 + 32) * HDIM + cs * 8, &kS[wave * 512 + 2048]);
        gl_lds16(VT + vtbase + (size_t)r0        * T_SEQ + kb + cs * 8, &vS[wave * 512]);
        gl_lds16(VT + vtbase + (size_t)(r0 + 32) * T_SEQ + kb + cs * 8, &vS[wave * 512 + 2048]);
        __syncthreads();   // drains vmcnt -> tiles valid

        const bool blkL = (kb <= q0L);       // wave-uniform

        // ---- QK^T from LDS K tile ----
        f32x4 sH[4], sL[4];
        #pragma unroll
        for (int s = 0; s < 4; s++) {
            const int kbs  = kb + s * 16;
            const int rowf = s * 16 + row;
            const bool needH = (kbs <= q0H);
            const bool needL = (kbs <= q0L);
            if (needH) {
                const bf16x8 kf0 = *(const bf16x8*)&kS[rowf * 64 + ((quad     + rowf) & 7) * 8];
                const bf16x8 kf1 = *(const bf16x8*)&kS[rowf * 64 + ((quad + 4 + rowf) & 7) * 8];
                f32x4 t = z;
                t = __builtin_amdgcn_mfma_f32_16x16x32_bf16(kf0, qH0, t, 0, 0, 0);
                t = __builtin_amdgcn_mfma_f32_16x16x32_bf16(kf1, qH1, t, 0, 0, 0);
                if (kbs == q0H) {
                    #pragma unroll
                    for (int r = 0; r < 4; r++)
                        if (quad * 4 + r > row) t[r] = -1e30f;
                }
                sH[s] = t;
                if (needL) {
                    f32x4 u = z;
                    u = __builtin_amdgcn_mfma_f32_16x16x32_bf16(kf0, qL0, u, 0, 0, 0);
                    u = __builtin_amdgcn_mfma_f32_16x16x32_bf16(kf1, qL1, u, 0, 0, 0);
                    if (kbs == q0L) {
                        #pragma unroll
                        for (int r = 0; r < 4; r++)
                            if (quad * 4 + r > row) u[r] = -1e30f;
                    }
                    sL[s] = u;
                } else {
                    #pragma unroll
                    for (int r = 0; r < 4; r++) sL[s][r] = -1e30f;
                }
            } else {
                #pragma unroll
                for (int r = 0; r < 4; r++) { sH[s][r] = -1e30f; sL[s][r] = -1e30f; }
            }
        }

        // ---- online softmax (exp2 domain), tile H ----
        bf16x4 pfH[4];
        {
            float mc = -1e30f;
            #pragma unroll
            for (int s = 0; s < 4; s++)
                #pragma unroll
                for (int r = 0; r < 4; r++) mc = fmaxf(mc, sH[s][r]);
            mc = fmaxf(mc, __shfl_xor(mc, 16));
            mc = fmaxf(mc, __shfl_xor(mc, 32));
            const float mn    = fmaxf(mH, mc);
            const float alpha = exp2f(mH - mn);
            float ps = 0.f;
            #pragma unroll
            for (int s = 0; s < 4; s++) {
                #pragma unroll
                for (int r = 0; r < 4; r++) {
                    const float pv = exp2f(sH[s][r] - mn);
                    pfH[s][r] = (short)f2b(pv);
                    ps += pv;
                }
            }
            ps += __shfl_xor(ps, 16);
            ps += __shfl_xor(ps, 32);
            lH = lH * alpha + ps;
            mH = mn;
            #pragma unroll
            for (int dt = 0; dt < 4; dt++)
                #pragma unroll
                for (int r = 0; r < 4; r++) oH[dt][r] *= alpha;
        }

        // ---- online softmax (exp2 domain), tile L ----
        bf16x4 pfL[4];
        if (blkL) {
            float mc = -1e30f;
            #pragma unroll
            for (int s = 0; s < 4; s++)
                #pragma unroll
                for (int r = 0; r < 4; r++) mc = fmaxf(mc, sL[s][r]);
            mc = fmaxf(mc, __shfl_xor(mc, 16));
            mc = fmaxf(mc, __shfl_xor(mc, 32));
            const float mn    = fmaxf(mL, mc);
            const float alpha = exp2f(mL - mn);
            float ps = 0.f;
            #pragma unroll
            for (int s = 0; s < 4; s++) {
                #pragma unroll
                for (int r = 0; r < 4; r++) {
                    const float pv = exp2f(sL[s][r] - mn);
                    pfL[s][r] = (short)f2b(pv);
                    ps += pv;
                }
            }
            ps += __shfl_xor(ps, 16);
            ps += __shfl_xor(ps, 32);
            lL = lL * alpha + ps;
            mL = mn;
            #pragma unroll
            for (int dt = 0; dt < 4; dt++)
                #pragma unroll
                for (int r = 0; r < 4; r++) oL[dt][r] *= alpha;
        }

        // ---- PV from LDS V^T tile ----
        #pragma unroll
        for (int s = 0; s < 4; s++) {
            const int kbs = kb + s * 16;
            if (kbs <= q0H) {
                const bool doL = (kbs <= q0L);
                #pragma unroll
                for (int dt = 0; dt < 4; dt++) {
                    const int drow = dt * 16 + row;
                    const bf16x4 vf = *(const bf16x4*)&vS[
                        drow * 64 + ((2 * s + (quad >> 1) + drow) & 7) * 8 + (quad & 1) * 4];
                    oH[dt] = __builtin_amdgcn_mfma_f32_16x16x16bf16_1k(vf, pfH[s], oH[dt], 0, 0, 0);
                    if (doL)
                        oL[dt] = __builtin_amdgcn_mfma_f32_16x16x16bf16_1k(vf, pfL[s], oL[dt], 0, 0, 0);
                }
            }
        }
    }

    // ---- epilogue: both tiles ----
    {
        const float rl = 1.f / lH;
        unsigned short* op = Out + ((size_t)(b * T_SEQ + q0H + row)) * DMODEL + h * HDIM + quad * 4;
        #pragma unroll
        for (int dt = 0; dt < 4; dt++) {
            ushort4 pk;
            pk.x = f2b(oH[dt][0] * rl);
            pk.y = f2b(oH[dt][1] * rl);
            pk.z = f2b(oH[dt][2] * rl);
            pk.w = f2b(oH[dt][3] * rl);
            *(ushort4*)(op + dt * 16) = pk;
        }
    }
    {
        const float rl = 1.f / lL;
        unsigned short* op = Out + ((size_t)(b * T_SEQ + q0L + row)) * DMODEL + h * HDIM + quad * 4;
        #pragma unroll
        for (int dt = 0; dt < 4; dt++) {
            ushort4 pk;
            pk.x = f2b(oL[dt][0] * rl);
            pk.y = f2b(oL[dt][1] * rl);
            pk.z = f2b(oL[dt][2] * rl);
            pk.w = f2b(oL[dt][3] * rl);
            *(ushort4*)(op + dt * 16) = pk;
        }
    }
}

extern "C" void kernel_launch(void* const* d_in, const int* in_sizes, int n_in,
                              void* d_out, int out_size, void* d_ws, size_t ws_size,
                              hipStream_t stream)
{
    const float* x    = (const float*)d_in[0];
    const float* Wqkv = (const float*)d_in[1];
    const float* bqkv = (const float*)d_in[2];
    const float* Wout = (const float*)d_in[3];
    const float* bout = (const float*)d_in[4];
    float* out = (float*)d_out;

    // workspace (MiB offsets): xb 0..16 | WqkvT 16..22 | WoutT 22..24 |
    // Qb 24..40 | Kb 40..56 | Vt 56..72 | Ab 72..88
    char* ws = (char*)d_ws;
    unsigned short* xb    = (unsigned short*)(ws + (size_t)0  * 1024 * 1024);
    unsigned short* WqkvT = (unsigned short*)(ws + (size_t)16 * 1024 * 1024);
    unsigned short* WoutT = (unsigned short*)(ws + (size_t)22 * 1024 * 1024);
    unsigned short* Qb    = (unsigned short*)(ws + (size_t)24 * 1024 * 1024);
    unsigned short* Kb    = (unsigned short*)(ws + (size_t)40 * 1024 * 1024);
    unsigned short* Vt    = (unsigned short*)(ws + (size_t)56 * 1024 * 1024);
    unsigned short* Ab    = (unsigned short*)(ws + (size_t)72 * 1024 * 1024);

    // 0) converts / transposes
    cvt_bf16<<<dim3(MROWS * DMODEL / 1024), 256, 0, stream>>>(x, xb, MROWS * DMODEL);
    cvt_tr<<<dim3(3 * DMODEL / 32, DMODEL / 32), 256, 0, stream>>>(Wqkv, WqkvT, DMODEL, 3 * DMODEL);
    cvt_tr<<<dim3(DMODEL / 32, DMODEL / 32), 256, 0, stream>>>(Wout, WoutT, DMODEL, DMODEL);

    // 1) qkv = x @ W_qkv + b_qkv -> Qb (scaled, log2e folded), Kb, Vt
    gemm_mfma<<<dim3(3 * DMODEL / 128, MROWS / 128), 256, 0, stream>>>(
        xb, WqkvT, bqkv, 3 * DMODEL, DMODEL, 0, Qb, Kb, Vt, nullptr);

    // 2) causal MFMA flash attention -> Ab bf16
    attn_mfma<<<dim3(BATCH * NHEADS, 16), 256, 0, stream>>>(Qb, Kb, Vt, Ab);

    // 3) out = Ab @ W_out + b_out (fp32 out)
    gemm_mfma<<<dim3(DMODEL / 128, MROWS / 128), 256, 0, stream>>>(
        Ab, WoutT, bout, DMODEL, DMODEL, 1, nullptr, nullptr, nullptr, out);
}

// Round 12
// 394.184 us; speedup vs baseline: 1.0335x; 1.0335x over previous
//
#include <hip/hip_runtime.h>
#include <stdint.h>

#define T_SEQ   2048
#define DMODEL  1024
#define NHEADS  16
#define HDIM    64
#define BATCH   4
#define MROWS   (BATCH * T_SEQ)   // 8192
// Q pre-scale: 1/sqrt(64) * log2(e)  (softmax runs in exp2 domain)
#define QSCALE  0.18033688011112042f

typedef __attribute__((ext_vector_type(4))) short bf16x4;
typedef __attribute__((ext_vector_type(8))) short bf16x8;
typedef __attribute__((ext_vector_type(4))) float f32x4;

__device__ __forceinline__ float b2f(unsigned short u) {
    union { unsigned int i; float f; } x;
    x.i = ((unsigned int)u) << 16;
    return x.f;
}

__device__ __forceinline__ unsigned short f2b(float f) {
    union { float f; unsigned int i; } x;
    x.f = f;
    unsigned int r = x.i + 0x7FFFu + ((x.i >> 16) & 1u);  // RNE
    return (unsigned short)(r >> 16);
}

// raw v_exp_f32 (input in log2 domain)
__device__ __forceinline__ float fexp2(float x) {
#if __has_builtin(__builtin_amdgcn_exp2f)
    return __builtin_amdgcn_exp2f(x);
#else
    return __expf(x * 0.6931471805599453f);
#endif
}

// pack two fp32 -> packed bf16 pair (low = a, high = b)
__device__ __forceinline__ unsigned int pack2(float a, float b) {
#if __has_builtin(__builtin_amdgcn_cvt_pk_bf16_f32)
    auto r = __builtin_amdgcn_cvt_pk_bf16_f32(a, b);
    unsigned int u;
    __builtin_memcpy(&u, &r, 4);
    return u;
#else
    return ((unsigned int)f2b(a)) | (((unsigned int)f2b(b)) << 16);
#endif
}

// async global->LDS, 16 B per lane; dest = lds base (wave-uniform) + lane*16
__device__ __forceinline__ void gl_lds16(const unsigned short* g, unsigned short* l) {
    __builtin_amdgcn_global_load_lds(
        (const __attribute__((address_space(1))) void*)g,
        (__attribute__((address_space(3))) void*)l,
        16, 0, 0);
}

// ---------------------------------------------------------------------------
// fp32 -> bf16 elementwise convert
// ---------------------------------------------------------------------------
__global__ __launch_bounds__(256) void cvt_bf16(
    const float* __restrict__ in, unsigned short* __restrict__ out, int n)
{
    const int i = (blockIdx.x * 256 + threadIdx.x) * 4;
    if (i + 3 < n) {
        const float4 v = *(const float4*)(in + i);
        ushort4 o;
        o.x = f2b(v.x); o.y = f2b(v.y); o.z = f2b(v.z); o.w = f2b(v.w);
        *(ushort4*)(out + i) = o;
    }
}

// ---------------------------------------------------------------------------
// fp32 [K][N] -> bf16 [N][K] transpose+convert, 32x32 LDS tile
// ---------------------------------------------------------------------------
__global__ __launch_bounds__(256) void cvt_tr(
    const float* __restrict__ W, unsigned short* __restrict__ WT, int K, int N)
{
    __shared__ unsigned short s[32][33];
    const int n0 = blockIdx.x * 32, k0 = blockIdx.y * 32;
    const int tx = threadIdx.x & 31, ty = threadIdx.x >> 5;   // ty 0..7
    #pragma unroll
    for (int i = 0; i < 4; i++)
        s[ty + 8 * i][tx] = f2b(W[(size_t)(k0 + ty + 8 * i) * N + n0 + tx]);
    __syncthreads();
    #pragma unroll
    for (int i = 0; i < 4; i++)
        WT[(size_t)(n0 + ty + 8 * i) * K + k0 + tx] = s[tx][ty + 8 * i];
}

// ---------------------------------------------------------------------------
// bf16 MFMA GEMM: C[M][N] = A[M][Kd] * BT[N][Kd]^T + bias[N]
// 128x128 tile, BK=32, 256 thr = 4 waves (2x2), each wave 64x64 = 4x4 MFMAs.
// Staging via global_load_lds (16B/lane), source-side swizzle. (R11, neutral)
// ---------------------------------------------------------------------------
__global__ __launch_bounds__(256) void gemm_mfma(
    const unsigned short* __restrict__ A,
    const unsigned short* __restrict__ BT,
    const float* __restrict__ bias,
    int N, int Kd, int mode,
    unsigned short* __restrict__ Oq,
    unsigned short* __restrict__ Ok,
    unsigned short* __restrict__ Ov,
    float* __restrict__ Of)
{
    __shared__ __align__(16) unsigned short aS[128 * 32];
    __shared__ __align__(16) unsigned short bS[128 * 32];

    const int tid  = threadIdx.x;
    const int lane = tid & 63;
    const int wave = tid >> 6;
    const int row  = lane & 15;
    const int quad = lane >> 4;
    const int wm   = wave >> 1;
    const int wn   = wave & 1;
    const int m0   = blockIdx.y * 128;
    const int n0   = blockIdx.x * 128;

    const int srow = lane >> 2;                 // 0..15
    const int kq   = lane & 3;
    const int cs   = (kq - (srow >> 1)) & 3;    // source chunk for dest slot kq
    const int frd  = row * 32 + (((quad + (row >> 1)) & 3) * 8);

    f32x4 acc[4][4];
    const f32x4 z = {0.f, 0.f, 0.f, 0.f};
    #pragma unroll
    for (int i = 0; i < 4; i++)
        #pragma unroll
        for (int j = 0; j < 4; j++) acc[i][j] = z;

    for (int k0 = 0; k0 < Kd; k0 += 32) {
        __syncthreads();   // all waves done reading previous tile
        gl_lds16(A  + (size_t)(m0 + wave * 16       + srow) * Kd + k0 + cs * 8, &aS[wave * 512]);
        gl_lds16(A  + (size_t)(m0 + (wave + 4) * 16 + srow) * Kd + k0 + cs * 8, &aS[wave * 512 + 2048]);
        gl_lds16(BT + (size_t)(n0 + wave * 16       + srow) * Kd + k0 + cs * 8, &bS[wave * 512]);
        gl_lds16(BT + (size_t)(n0 + (wave + 4) * 16 + srow) * Kd + k0 + cs * 8, &bS[wave * 512 + 2048]);
        __syncthreads();   // drains vmcnt -> LDS valid

        bf16x8 af[4], bf[4];
        #pragma unroll
        for (int t = 0; t < 4; t++) {
            af[t] = *(const bf16x8*)(aS + (wm * 4 + t) * 512 + frd);
            bf[t] = *(const bf16x8*)(bS + (wn * 4 + t) * 512 + frd);
        }
        #pragma unroll
        for (int i = 0; i < 4; i++)
            #pragma unroll
            for (int j = 0; j < 4; j++)
                acc[i][j] = __builtin_amdgcn_mfma_f32_16x16x32_bf16(af[i], bf[j], acc[i][j], 0, 0, 0);
    }

    if (mode == 0) {
        #pragma unroll
        for (int j = 0; j < 4; j++) {
            const int n  = n0 + wn * 64 + j * 16 + row;
            const float bi = bias[n];
            const int which = n >> 10;
            const int rem   = n & 1023;
            const int h     = rem >> 6;
            const int d     = rem & 63;
            #pragma unroll
            for (int i = 0; i < 4; i++) {
                const int mbase = m0 + wm * 64 + i * 16 + quad * 4;
                #pragma unroll
                for (int r = 0; r < 4; r++) {
                    const int m = mbase + r;
                    const int b = m >> 11;
                    const int t = m & 2047;
                    const int bh = b * NHEADS + h;
                    const float v = acc[i][j][r] + bi;
                    if (which == 0) {
                        Oq[((size_t)bh * T_SEQ + t) * HDIM + d] = f2b(v * QSCALE);
                    } else if (which == 1) {
                        Ok[((size_t)bh * T_SEQ + t) * HDIM + d] = f2b(v);
                    } else {
                        Ov[((size_t)bh * HDIM + d) * T_SEQ + t] = f2b(v);
                    }
                }
            }
        }
    } else {
        #pragma unroll
        for (int j = 0; j < 4; j++) {
            const int n  = n0 + wn * 64 + j * 16 + row;
            const float bi = bias[n];
            #pragma unroll
            for (int i = 0; i < 4; i++) {
                const int mbase = m0 + wm * 64 + i * 16 + quad * 4;
                #pragma unroll
                for (int r = 0; r < 4; r++)
                    Of[(size_t)(mbase + r) * N + n] = acc[i][j][r] + bi;
            }
        }
    }
}

// ---------------------------------------------------------------------------
// MFMA flash attention: R10 structure (register-prefetch double-buffered
// K/V LDS tiles, stride-72 pad, WG-level pairing) + exp2-domain softmax via
// raw v_exp_f32 + hardware packed bf16 cvt for the P fragments.
// ---------------------------------------------------------------------------
__global__ __launch_bounds__(256) void attn_mfma(
    const unsigned short* __restrict__ Q,   // [bh][t][64] bf16 (scaled, log2e)
    const unsigned short* __restrict__ K,   // [bh][t][64] bf16
    const unsigned short* __restrict__ VT,  // [bh][64][T] bf16
    unsigned short* __restrict__ Out)       // [B*T][DMODEL] bf16
{
    __shared__ __align__(16) unsigned short kS[2][64 * 72];
    __shared__ __align__(16) unsigned short vS[2][64 * 72];

    const int tid  = threadIdx.x;
    const int lane = tid & 63;
    const int wave = tid >> 6;
    const int row  = lane & 15;
    const int quad = lane >> 4;

    const int bh = blockIdx.x;
    const int b  = bh >> 4;
    const int h  = bh & 15;
    const int P  = blockIdx.y;                 // 0..15
    const int q0L = 64 * P + 16 * wave;
    const int q0H = 64 * (31 - P) + 16 * wave;
    const int kend = 64 * (31 - P) + 64;       // WG-uniform loop bound

    const size_t qkbase = (size_t)bh * T_SEQ * HDIM;
    const size_t vtbase = (size_t)bh * HDIM * T_SEQ;

    // staging geometry: pass covers 2048 elems; thread -> (krow, chunk)
    const int krow0 = tid >> 3;          // 0..31
    const int c0    = tid & 7;           // 0..7
    const int lds0  = krow0 * 72 + c0 * 8;
    const int lds1  = (krow0 + 32) * 72 + c0 * 8;
    const int flat0 = tid * 8;           // = krow0*64 + c0*8

    // Q fragments
    const unsigned short* qpL = Q + qkbase + (size_t)(q0L + row) * HDIM + quad * 8;
    const bf16x8 qL0 = *(const bf16x8*)qpL;
    const bf16x8 qL1 = *(const bf16x8*)(qpL + 32);
    const unsigned short* qpH = Q + qkbase + (size_t)(q0H + row) * HDIM + quad * 8;
    const bf16x8 qH0 = *(const bf16x8*)qpH;
    const bf16x8 qH1 = *(const bf16x8*)(qpH + 32);

    const f32x4 z = {0.f, 0.f, 0.f, 0.f};
    f32x4 oL[4] = {z, z, z, z};
    f32x4 oH[4] = {z, z, z, z};
    float mL = -1e30f, lL = 0.f, mH = -1e30f, lH = 0.f;

    // prefetch tile 0
    uint4 pk0 = *(const uint4*)(K  + qkbase + flat0);
    uint4 pk1 = *(const uint4*)(K  + qkbase + flat0 + 2048);
    uint4 pv0 = *(const uint4*)(VT + vtbase + (size_t)krow0        * T_SEQ + c0 * 8);
    uint4 pv1 = *(const uint4*)(VT + vtbase + (size_t)(krow0 + 32) * T_SEQ + c0 * 8);

    int buf = 0;
    for (int kb = 0; kb < kend; kb += 64) {
        // write staged tile to LDS[buf]
        *(uint4*)&kS[buf][lds0] = pk0;
        *(uint4*)&kS[buf][lds1] = pk1;
        *(uint4*)&vS[buf][lds0] = pv0;
        *(uint4*)&vS[buf][lds1] = pv1;
        __syncthreads();

        // prefetch next tile (overlaps with compute below)
        if (kb + 64 < kend) {
            const int kn = kb + 64;
            pk0 = *(const uint4*)(K  + qkbase + (size_t)kn * HDIM + flat0);
            pk1 = *(const uint4*)(K  + qkbase + (size_t)kn * HDIM + flat0 + 2048);
            pv0 = *(const uint4*)(VT + vtbase + (size_t)krow0        * T_SEQ + kn + c0 * 8);
            pv1 = *(const uint4*)(VT + vtbase + (size_t)(krow0 + 32) * T_SEQ + kn + c0 * 8);
        }

        const bool blkL = (kb <= q0L);       // wave-uniform

        // ---- QK^T from LDS K tile ----
        f32x4 sH[4], sL[4];
        #pragma unroll
        for (int s = 0; s < 4; s++) {
            const int kbs = kb + s * 16;
            const bool needH = (kbs <= q0H);
            const bool needL = (kbs <= q0L);
            if (needH) {
                const unsigned short* kp = &kS[buf][(s * 16 + row) * 72 + quad * 8];
                const bf16x8 kf0 = *(const bf16x8*)kp;
                const bf16x8 kf1 = *(const bf16x8*)(kp + 32);
                f32x4 t = z;
                t = __builtin_amdgcn_mfma_f32_16x16x32_bf16(kf0, qH0, t, 0, 0, 0);
                t = __builtin_amdgcn_mfma_f32_16x16x32_bf16(kf1, qH1, t, 0, 0, 0);
                if (kbs == q0H) {
                    #pragma unroll
                    for (int r = 0; r < 4; r++)
                        if (quad * 4 + r > row) t[r] = -1e30f;
                }
                sH[s] = t;
                if (needL) {
                    f32x4 u = z;
                    u = __builtin_amdgcn_mfma_f32_16x16x32_bf16(kf0, qL0, u, 0, 0, 0);
                    u = __builtin_amdgcn_mfma_f32_16x16x32_bf16(kf1, qL1, u, 0, 0, 0);
                    if (kbs == q0L) {
                        #pragma unroll
                        for (int r = 0; r < 4; r++)
                            if (quad * 4 + r > row) u[r] = -1e30f;
                    }
                    sL[s] = u;
                } else {
                    #pragma unroll
                    for (int r = 0; r < 4; r++) sL[s][r] = -1e30f;
                }
            } else {
                #pragma unroll
                for (int r = 0; r < 4; r++) { sH[s][r] = -1e30f; sL[s][r] = -1e30f; }
            }
        }

        // ---- online softmax (exp2 domain), tile H ----
        bf16x4 pfH[4];
        {
            float mc = -1e30f;
            #pragma unroll
            for (int s = 0; s < 4; s++)
                #pragma unroll
                for (int r = 0; r < 4; r++) mc = fmaxf(mc, sH[s][r]);
            mc = fmaxf(mc, __shfl_xor(mc, 16));
            mc = fmaxf(mc, __shfl_xor(mc, 32));
            const float mn    = fmaxf(mH, mc);
            const float alpha = fexp2(mH - mn);
            float ps = 0.f;
            #pragma unroll
            for (int s = 0; s < 4; s++) {
                const float p0 = fexp2(sH[s][0] - mn);
                const float p1 = fexp2(sH[s][1] - mn);
                const float p2 = fexp2(sH[s][2] - mn);
                const float p3 = fexp2(sH[s][3] - mn);
                ps += (p0 + p1) + (p2 + p3);
                uint2 u;
                u.x = pack2(p0, p1);
                u.y = pack2(p2, p3);
                pfH[s] = *(bf16x4*)&u;
            }
            ps += __shfl_xor(ps, 16);
            ps += __shfl_xor(ps, 32);
            lH = lH * alpha + ps;
            mH = mn;
            #pragma unroll
            for (int dt = 0; dt < 4; dt++)
                #pragma unroll
                for (int r = 0; r < 4; r++) oH[dt][r] *= alpha;
        }

        // ---- online softmax (exp2 domain), tile L ----
        bf16x4 pfL[4];
        if (blkL) {
            float mc = -1e30f;
            #pragma unroll
            for (int s = 0; s < 4; s++)
                #pragma unroll
                for (int r = 0; r < 4; r++) mc = fmaxf(mc, sL[s][r]);
            mc = fmaxf(mc, __shfl_xor(mc, 16));
            mc = fmaxf(mc, __shfl_xor(mc, 32));
            const float mn    = fmaxf(mL, mc);
            const float alpha = fexp2(mL - mn);
            float ps = 0.f;
            #pragma unroll
            for (int s = 0; s < 4; s++) {
                const float p0 = fexp2(sL[s][0] - mn);
                const float p1 = fexp2(sL[s][1] - mn);
                const float p2 = fexp2(sL[s][2] - mn);
                const float p3 = fexp2(sL[s][3] - mn);
                ps += (p0 + p1) + (p2 + p3);
                uint2 u;
                u.x = pack2(p0, p1);
                u.y = pack2(p2, p3);
                pfL[s] = *(bf16x4*)&u;
            }
            ps += __shfl_xor(ps, 16);
            ps += __shfl_xor(ps, 32);
            lL = lL * alpha + ps;
            mL = mn;
            #pragma unroll
            for (int dt = 0; dt < 4; dt++)
                #pragma unroll
                for (int r = 0; r < 4; r++) oL[dt][r] *= alpha;
        }

        // ---- PV from LDS V^T tile ----
        #pragma unroll
        for (int s = 0; s < 4; s++) {
            const int kbs = kb + s * 16;
            if (kbs <= q0H) {
                const bool doL = (kbs <= q0L);
                #pragma unroll
                for (int dt = 0; dt < 4; dt++) {
                    const bf16x4 vf = *(const bf16x4*)&vS[buf][
                        (dt * 16 + row) * 72 + (s * 2 + (quad >> 1)) * 8 + (quad & 1) * 4];
                    oH[dt] = __builtin_amdgcn_mfma_f32_16x16x16bf16_1k(vf, pfH[s], oH[dt], 0, 0, 0);
                    if (doL)
                        oL[dt] = __builtin_amdgcn_mfma_f32_16x16x16bf16_1k(vf, pfL[s], oL[dt], 0, 0, 0);
                }
            }
        }

        buf ^= 1;
    }

    // ---- epilogue: both tiles ----
    {
        const float rl = 1.f / lH;
        unsigned short* op = Out + ((size_t)(b * T_SEQ + q0H + row)) * DMODEL + h * HDIM + quad * 4;
        #pragma unroll
        for (int dt = 0; dt < 4; dt++) {
            uint2 u;
            u.x = pack2(oH[dt][0] * rl, oH[dt][1] * rl);
            u.y = pack2(oH[dt][2] * rl, oH[dt][3] * rl);
            *(uint2*)(op + dt * 16) = u;
        }
    }
    {
        const float rl = 1.f / lL;
        unsigned short* op = Out + ((size_t)(b * T_SEQ + q0L + row)) * DMODEL + h * HDIM + quad * 4;
        #pragma unroll
        for (int dt = 0; dt < 4; dt++) {
            uint2 u;
            u.x = pack2(oL[dt][0] * rl, oL[dt][1] * rl);
            u.y = pack2(oL[dt][2] * rl, oL[dt][3] * rl);
            *(uint2*)(op + dt * 16) = u;
        }
    }
}

extern "C" void kernel_launch(void* const* d_in, const int* in_sizes, int n_in,
                              void* d_out, int out_size, void* d_ws, size_t ws_size,
                              hipStream_t stream)
{
    const float* x    = (const float*)d_in[0];
    const float* Wqkv = (const float*)d_in[1];
    const float* bqkv = (const float*)d_in[2];
    const float* Wout = (const float*)d_in[3];
    const float* bout = (const float*)d_in[4];
    float* out = (float*)d_out;

    // workspace (MiB offsets): xb 0..16 | WqkvT 16..22 | WoutT 22..24 |
    // Qb 24..40 | Kb 40..56 | Vt 56..72 | Ab 72..88
    char* ws = (char*)d_ws;
    unsigned short* xb    = (unsigned short*)(ws + (size_t)0  * 1024 * 1024);
    unsigned short* WqkvT = (unsigned short*)(ws + (size_t)16 * 1024 * 1024);
    unsigned short* WoutT = (unsigned short*)(ws + (size_t)22 * 1024 * 1024);
    unsigned short* Qb    = (unsigned short*)(ws + (size_t)24 * 1024 * 1024);
    unsigned short* Kb    = (unsigned short*)(ws + (size_t)40 * 1024 * 1024);
    unsigned short* Vt    = (unsigned short*)(ws + (size_t)56 * 1024 * 1024);
    unsigned short* Ab    = (unsigned short*)(ws + (size_t)72 * 1024 * 1024);

    // 0) converts / transposes
    cvt_bf16<<<dim3(MROWS * DMODEL / 1024), 256, 0, stream>>>(x, xb, MROWS * DMODEL);
    cvt_tr<<<dim3(3 * DMODEL / 32, DMODEL / 32), 256, 0, stream>>>(Wqkv, WqkvT, DMODEL, 3 * DMODEL);
    cvt_tr<<<dim3(DMODEL / 32, DMODEL / 32), 256, 0, stream>>>(Wout, WoutT, DMODEL, DMODEL);

    // 1) qkv = x @ W_qkv + b_qkv -> Qb (scaled, log2e folded), Kb, Vt
    gemm_mfma<<<dim3(3 * DMODEL / 128, MROWS / 128), 256, 0, stream>>>(
        xb, WqkvT, bqkv, 3 * DMODEL, DMODEL, 0, Qb, Kb, Vt, nullptr);

    // 2) causal MFMA flash attention -> Ab bf16
    attn_mfma<<<dim3(BATCH * NHEADS, 16), 256, 0, stream>>>(Qb, Kb, Vt, Ab);

    // 3) out = Ab @ W_out + b_out (fp32 out)
    gemm_mfma<<<dim3(DMODEL / 128, MROWS / 128), 256, 0, stream>>>(
        Ab, WoutT, bout, DMODEL, DMODEL, 1, nullptr, nullptr, nullptr, out);
}